// Round 6
// baseline (68.502 us; speedup 1.0000x reference)
//
#include <hip/hip_runtime.h>
#include <math.h>

// ChamferLoss: B=16, M=N=2048, fp32 2-D points.
// Round-5 lesson: wave-uniform ds_read_b128 was DS-PIPE-bound (4096 insts/CU
// x ~12 cyc = 20.5 us > VALU floor 7.7 us). Fix: 4 queries per lane -> one
// ds_read_b128 (2 ref pts) feeds 8 pairs/lane = 36 VALU inst per DS inst.
// DS insts drop 4x: 1024/CU x 12 cyc = 5.1 us < VALU 7.7 us -> VALU-bound.
// Block = 256 queries x full 2048-ref set; 8 waves split refs into 256-pt
// slices; grid (8,16,2) = 256 blocks (1/CU, 2 waves/SIMD; throughput loop
// with 4 independent min3 chains so thin occupancy is fine).

#define CH_B    16
#define CH_N    2048
#define THREADS 512
#define WAVES   8
#define QPL     4                     // queries per lane
#define QPB     (QPL * 64)            // 256 queries per block
#define RPW     (CH_N / WAVES)        // 256 refs per wave slice
#define GRID_X  (CH_N / QPB)          // 8
#define NPART   (GRID_X * CH_B * 2)   // 256 partials

__global__ __launch_bounds__(THREADS) void chamfer_main_kernel(
    const float2* __restrict__ tp, const float2* __restrict__ ap,
    float* __restrict__ partials)
{
    __shared__ float2 spts[CH_N];        // 16 KB staged reference set
    __shared__ float  smin[WAVES][QPB];  // 8 KB per-wave per-query slice mins
    __shared__ float  ssum[QPL];

    const int tid  = threadIdx.x;
    const int lane = tid & 63;
    const int w    = tid >> 6;
    const int b    = blockIdx.y;
    const int dir  = blockIdx.z;         // 0: target->actual, 1: actual->target

    const float2* q = dir ? ap : tp;
    const float2* r = dir ? tp : ap;

    // 4 queries per lane: query j*64+lane (coalesced float2 loads; the 8x
    // redundancy across waves hits L1/L2 -- negligible).
    const float2* qb = q + (size_t)b * CH_N + blockIdx.x * QPB;
    float qx0, qy0, qx1, qy1, qx2, qy2, qx3, qy3;
    { float2 t = qb[0 * 64 + lane]; qx0 = t.x; qy0 = t.y; }
    { float2 t = qb[1 * 64 + lane]; qx1 = t.x; qy1 = t.y; }
    { float2 t = qb[2 * 64 + lane]; qx2 = t.x; qy2 = t.y; }
    { float2 t = qb[3 * 64 + lane]; qx3 = t.x; qy3 = t.y; }

    // Stage the full reference set: 512 threads x 2 float4 (2 pts each).
    const float4* rsrc = (const float4*)(r + (size_t)b * CH_N);
    float4* sdst = (float4*)spts;
    #pragma unroll
    for (int k = 0; k < (CH_N / 2) / THREADS; ++k)      // 2 iters
        sdst[tid + k * THREADS] = rsrc[tid + k * THREADS];
    __syncthreads();

    // Sweep this wave's 256-ref slice: 128 wave-uniform float4 reads,
    // 4 points (2 reads) per unrolled step.
    const float4* sp4 = (const float4*)spts + w * (RPW / 2);
    float a0 = 3.4e38f, a1 = 3.4e38f, a2 = 3.4e38f, a3 = 3.4e38f;
    #pragma unroll 2
    for (int i = 0; i < RPW / 2; i += 2) {
        float4 p0 = sp4[i + 0];
        float4 p1 = sp4[i + 1];
        float dx, dy, da, db, dc, dd;
        // query 0
        dx = qx0 - p0.x; dy = qy0 - p0.y; da = fmaf(dy, dy, dx * dx);
        dx = qx0 - p0.z; dy = qy0 - p0.w; db = fmaf(dy, dy, dx * dx);
        dx = qx0 - p1.x; dy = qy0 - p1.y; dc = fmaf(dy, dy, dx * dx);
        dx = qx0 - p1.z; dy = qy0 - p1.w; dd = fmaf(dy, dy, dx * dx);
        a0 = fminf(fminf(a0, da), db);                 // v_min3
        a0 = fminf(fminf(a0, dc), dd);
        // query 1
        dx = qx1 - p0.x; dy = qy1 - p0.y; da = fmaf(dy, dy, dx * dx);
        dx = qx1 - p0.z; dy = qy1 - p0.w; db = fmaf(dy, dy, dx * dx);
        dx = qx1 - p1.x; dy = qy1 - p1.y; dc = fmaf(dy, dy, dx * dx);
        dx = qx1 - p1.z; dy = qy1 - p1.w; dd = fmaf(dy, dy, dx * dx);
        a1 = fminf(fminf(a1, da), db);
        a1 = fminf(fminf(a1, dc), dd);
        // query 2
        dx = qx2 - p0.x; dy = qy2 - p0.y; da = fmaf(dy, dy, dx * dx);
        dx = qx2 - p0.z; dy = qy2 - p0.w; db = fmaf(dy, dy, dx * dx);
        dx = qx2 - p1.x; dy = qy2 - p1.y; dc = fmaf(dy, dy, dx * dx);
        dx = qx2 - p1.z; dy = qy2 - p1.w; dd = fmaf(dy, dy, dx * dx);
        a2 = fminf(fminf(a2, da), db);
        a2 = fminf(fminf(a2, dc), dd);
        // query 3
        dx = qx3 - p0.x; dy = qy3 - p0.y; da = fmaf(dy, dy, dx * dx);
        dx = qx3 - p0.z; dy = qy3 - p0.w; db = fmaf(dy, dy, dx * dx);
        dx = qx3 - p1.x; dy = qy3 - p1.y; dc = fmaf(dy, dy, dx * dx);
        dx = qx3 - p1.z; dy = qy3 - p1.w; dd = fmaf(dy, dy, dx * dx);
        a3 = fminf(fminf(a3, da), db);
        a3 = fminf(fminf(a3, dc), dd);
    }
    smin[w][0 * 64 + lane] = a0;
    smin[w][1 * 64 + lane] = a1;
    smin[w][2 * 64 + lane] = a2;
    smin[w][3 * 64 + lane] = a3;
    __syncthreads();

    // Waves 0..3: wave j combines the 8 ref-slices for query row j.
    if (w < QPL) {
        float v = smin[0][w * 64 + lane];
        #pragma unroll
        for (int ww = 1; ww < WAVES; ++ww)
            v = fminf(v, smin[ww][w * 64 + lane]);
        v = sqrtf(v);
        #pragma unroll
        for (int off = 1; off < 64; off <<= 1)
            v += __shfl_xor(v, off);
        if (lane == 0) ssum[w] = v;
    }
    __syncthreads();
    if (tid == 0)
        partials[((size_t)dir * CH_B + b) * GRID_X + blockIdx.x] =
            ssum[0] + ssum[1] + ssum[2] + ssum[3];
}

__global__ __launch_bounds__(64) void chamfer_reduce_kernel(
    const float* __restrict__ partials, float* __restrict__ out, float scale)
{
    const int tid = threadIdx.x;
    const float4* p4 = (const float4*)partials;   // 256 floats = 64 float4
    float4 v = p4[tid];
    float s = v.x + v.y + v.z + v.w;
    #pragma unroll
    for (int off = 1; off < 64; off <<= 1)
        s += __shfl_xor(s, off);
    if (tid == 0) out[0] = s * scale;
}

extern "C" void kernel_launch(void* const* d_in, const int* in_sizes, int n_in,
                              void* d_out, int out_size, void* d_ws, size_t ws_size,
                              hipStream_t stream) {
    const float2* tp = (const float2*)d_in[0];  // target_points [B, M, 2]
    const float2* ap = (const float2*)d_in[1];  // actual_points [B, N, 2]
    float* out      = (float*)d_out;
    float* partials = (float*)d_ws;             // 256 floats, fully overwritten

    dim3 grid(GRID_X, CH_B, 2);                 // 256 blocks
    chamfer_main_kernel<<<grid, THREADS, 0, stream>>>(tp, ap, partials);

    const float scale = 1.0f / (float)(CH_B * CH_N);   // M == N == 2048
    chamfer_reduce_kernel<<<1, 64, 0, stream>>>(partials, out, scale);
}

// Round 7
// 67.882 us; speedup vs baseline: 1.0091x; 1.0091x over previous
//
#include <hip/hip_runtime.h>
#include <math.h>

// ChamferLoss: B=16, M=N=2048, fp32 2-D points.
// R5 lesson: DS traffic/CU = 4096/QPL b128-reads. R6 lesson: waves/SIMD =
// S/QPL (S = ref-split waves per block) -- raising QPL without S trades
// DS-bound for latency-bound. This round: QPL=4 AND S=16.
//   DS:  1024 reads/CU x 12 cyc = 5.1 us  (below VALU floor)
//   VALU: 4.5 inst/pair -> 18.4K cyc/SIMD = 7.7 us floor
//   occupancy: 256 blocks x 16 waves = 4 waves/SIMD (8 if 2 blocks/CU fit)
//   latency: 4 waves x ~144 cyc compute per 2-read group >> 120 cyc DS lat.

#define CH_B    16
#define CH_N    2048
#define THREADS 1024
#define WAVES   16                    // S: ref-split factor
#define QPL     4                     // queries per lane
#define QPB     (QPL * 64)            // 256 queries per block
#define RPW     (CH_N / WAVES)        // 128 refs per wave slice
#define GRID_X  (CH_N / QPB)          // 8
#define NPART   (GRID_X * CH_B * 2)   // 256 partials

__global__ __launch_bounds__(THREADS, 4) void chamfer_main_kernel(
    const float2* __restrict__ tp, const float2* __restrict__ ap,
    float* __restrict__ partials)
{
    __shared__ float2 spts[CH_N];        // 16 KB staged reference set
    __shared__ float  smin[WAVES][QPB];  // 16 KB per-wave per-query slice mins
    __shared__ float  ssum[QPL];

    const int tid  = threadIdx.x;
    const int lane = tid & 63;
    const int w    = tid >> 6;
    const int b    = blockIdx.y;
    const int dir  = blockIdx.z;         // 0: target->actual, 1: actual->target

    const float2* q = dir ? ap : tp;
    const float2* r = dir ? tp : ap;

    // 4 queries per lane (coalesced float2; 16x wave redundancy hits L1).
    const float2* qb = q + (size_t)b * CH_N + blockIdx.x * QPB;
    float qx0, qy0, qx1, qy1, qx2, qy2, qx3, qy3;
    { float2 t = qb[0 * 64 + lane]; qx0 = t.x; qy0 = t.y; }
    { float2 t = qb[1 * 64 + lane]; qx1 = t.x; qy1 = t.y; }
    { float2 t = qb[2 * 64 + lane]; qx2 = t.x; qy2 = t.y; }
    { float2 t = qb[3 * 64 + lane]; qx3 = t.x; qy3 = t.y; }

    // Stage the full reference set: 1024 threads x 1 float4 (2 pts each).
    ((float4*)spts)[tid] = ((const float4*)(r + (size_t)b * CH_N))[tid];
    __syncthreads();

    // Sweep this wave's 128-ref slice: 64 wave-uniform b128 reads,
    // 4 points (2 reads) per unrolled step.
    const float4* sp4 = (const float4*)spts + w * (RPW / 2);
    float a0 = 3.4e38f, a1 = 3.4e38f, a2 = 3.4e38f, a3 = 3.4e38f;
    #pragma unroll 2
    for (int i = 0; i < RPW / 2; i += 2) {
        float4 p0 = sp4[i + 0];
        float4 p1 = sp4[i + 1];
        float dx, dy, da, db, dc, dd;
        // query 0
        dx = qx0 - p0.x; dy = qy0 - p0.y; da = fmaf(dy, dy, dx * dx);
        dx = qx0 - p0.z; dy = qy0 - p0.w; db = fmaf(dy, dy, dx * dx);
        dx = qx0 - p1.x; dy = qy0 - p1.y; dc = fmaf(dy, dy, dx * dx);
        dx = qx0 - p1.z; dy = qy0 - p1.w; dd = fmaf(dy, dy, dx * dx);
        a0 = fminf(fminf(a0, da), db);                 // v_min3
        a0 = fminf(fminf(a0, dc), dd);
        // query 1
        dx = qx1 - p0.x; dy = qy1 - p0.y; da = fmaf(dy, dy, dx * dx);
        dx = qx1 - p0.z; dy = qy1 - p0.w; db = fmaf(dy, dy, dx * dx);
        dx = qx1 - p1.x; dy = qy1 - p1.y; dc = fmaf(dy, dy, dx * dx);
        dx = qx1 - p1.z; dy = qy1 - p1.w; dd = fmaf(dy, dy, dx * dx);
        a1 = fminf(fminf(a1, da), db);
        a1 = fminf(fminf(a1, dc), dd);
        // query 2
        dx = qx2 - p0.x; dy = qy2 - p0.y; da = fmaf(dy, dy, dx * dx);
        dx = qx2 - p0.z; dy = qy2 - p0.w; db = fmaf(dy, dy, dx * dx);
        dx = qx2 - p1.x; dy = qy2 - p1.y; dc = fmaf(dy, dy, dx * dx);
        dx = qx2 - p1.z; dy = qy2 - p1.w; dd = fmaf(dy, dy, dx * dx);
        a2 = fminf(fminf(a2, da), db);
        a2 = fminf(fminf(a2, dc), dd);
        // query 3
        dx = qx3 - p0.x; dy = qy3 - p0.y; da = fmaf(dy, dy, dx * dx);
        dx = qx3 - p0.z; dy = qy3 - p0.w; db = fmaf(dy, dy, dx * dx);
        dx = qx3 - p1.x; dy = qy3 - p1.y; dc = fmaf(dy, dy, dx * dx);
        dx = qx3 - p1.z; dy = qy3 - p1.w; dd = fmaf(dy, dy, dx * dx);
        a3 = fminf(fminf(a3, da), db);
        a3 = fminf(fminf(a3, dc), dd);
    }
    smin[w][0 * 64 + lane] = a0;
    smin[w][1 * 64 + lane] = a1;
    smin[w][2 * 64 + lane] = a2;
    smin[w][3 * 64 + lane] = a3;
    __syncthreads();

    // Waves 0..3: wave j combines the 16 ref-slices for query row j.
    // Each read: 64 consecutive floats across the wave -> 2-way bank (free).
    if (w < QPL) {
        float v = smin[0][w * 64 + lane];
        #pragma unroll
        for (int ww = 1; ww < WAVES; ++ww)
            v = fminf(v, smin[ww][w * 64 + lane]);
        v = sqrtf(v);
        #pragma unroll
        for (int off = 1; off < 64; off <<= 1)
            v += __shfl_xor(v, off);
        if (lane == 0) ssum[w] = v;
    }
    __syncthreads();
    if (tid == 0)
        partials[((size_t)dir * CH_B + b) * GRID_X + blockIdx.x] =
            ssum[0] + ssum[1] + ssum[2] + ssum[3];
}

__global__ __launch_bounds__(64) void chamfer_reduce_kernel(
    const float* __restrict__ partials, float* __restrict__ out, float scale)
{
    const int tid = threadIdx.x;
    const float4* p4 = (const float4*)partials;   // 256 floats = 64 float4
    float4 v = p4[tid];
    float s = v.x + v.y + v.z + v.w;
    #pragma unroll
    for (int off = 1; off < 64; off <<= 1)
        s += __shfl_xor(s, off);
    if (tid == 0) out[0] = s * scale;
}

extern "C" void kernel_launch(void* const* d_in, const int* in_sizes, int n_in,
                              void* d_out, int out_size, void* d_ws, size_t ws_size,
                              hipStream_t stream) {
    const float2* tp = (const float2*)d_in[0];  // target_points [B, M, 2]
    const float2* ap = (const float2*)d_in[1];  // actual_points [B, N, 2]
    float* out      = (float*)d_out;
    float* partials = (float*)d_ws;             // 256 floats, fully overwritten

    dim3 grid(GRID_X, CH_B, 2);                 // 256 blocks x 1024 threads
    chamfer_main_kernel<<<grid, THREADS, 0, stream>>>(tp, ap, partials);

    const float scale = 1.0f / (float)(CH_B * CH_N);   // M == N == 2048
    chamfer_reduce_kernel<<<1, 64, 0, stream>>>(partials, out, scale);
}

// Round 8
// 65.540 us; speedup vs baseline: 1.0452x; 1.0357x over previous
//
#include <hip/hip_runtime.h>
#include <math.h>

// ChamferLoss: B=16, M=N=2048, fp32 2-D points.
// R7 lesson: main stuck ~19.5us across 3 structures; occupancy & DS load
// proven non-binding (R6==R7). Cut VALU work instead:
//   min_n d2 = q^2 - max_n s,  s = 2(q.p) - (px^2+py^2)
// Per 4-ref x 4-query group: 2 ds_read_b128 + 8(g) + 32(fma) + 8(max) = 48
// VALU (was 72). Floors: VALU 5.1us, DS 5.1us (separate pipes, overlap).
// Shape unchanged from R7: 256 blocks x 16 waves, 4 queries/lane.

#define CH_B    16
#define CH_N    2048
#define THREADS 1024
#define WAVES   16                    // ref-split factor
#define QPL     4                     // queries per lane
#define QPB     (QPL * 64)            // 256 queries per block
#define RPW     (CH_N / WAVES)        // 128 refs per wave slice
#define GRID_X  (CH_N / QPB)          // 8
#define NPART   (GRID_X * CH_B * 2)   // 256 partials

__global__ __launch_bounds__(THREADS, 4) void chamfer_main_kernel(
    const float2* __restrict__ tp, const float2* __restrict__ ap,
    float* __restrict__ partials)
{
    __shared__ float2 spts[CH_N];        // 16 KB staged reference set (x,y pairs)
    __shared__ float  smin[WAVES][QPB];  // 16 KB per-wave per-query slice maxes
    __shared__ float  ssum[QPL];

    const int tid  = threadIdx.x;
    const int lane = tid & 63;
    const int w    = tid >> 6;
    const int b    = blockIdx.y;
    const int dir  = blockIdx.z;         // 0: target->actual, 1: actual->target

    const float2* q = dir ? ap : tp;
    const float2* r = dir ? tp : ap;

    // 4 queries per lane; precompute doubled coords and q^2.
    const float2* qb = q + (size_t)b * CH_N + blockIdx.x * QPB;
    float Qx0, Qy0, q20, Qx1, Qy1, q21, Qx2, Qy2, q22, Qx3, Qy3, q23;
    { float2 t = qb[0 * 64 + lane]; Qx0 = 2.f*t.x; Qy0 = 2.f*t.y; q20 = fmaf(t.x,t.x,t.y*t.y); }
    { float2 t = qb[1 * 64 + lane]; Qx1 = 2.f*t.x; Qy1 = 2.f*t.y; q21 = fmaf(t.x,t.x,t.y*t.y); }
    { float2 t = qb[2 * 64 + lane]; Qx2 = 2.f*t.x; Qy2 = 2.f*t.y; q22 = fmaf(t.x,t.x,t.y*t.y); }
    { float2 t = qb[3 * 64 + lane]; Qx3 = 2.f*t.x; Qy3 = 2.f*t.y; q23 = fmaf(t.x,t.x,t.y*t.y); }

    // Stage the full reference set: 1024 threads x 1 float4 (2 pts each).
    ((float4*)spts)[tid] = ((const float4*)(r + (size_t)b * CH_N))[tid];
    __syncthreads();

    // Sweep this wave's 128-ref slice: 64 wave-uniform b128 reads,
    // 4 points (2 reads) per step; s = 2 q.p - |p|^2, track max per query.
    const float4* sp4 = (const float4*)spts + w * (RPW / 2);
    float a0 = -3.4e38f, a1 = -3.4e38f, a2 = -3.4e38f, a3 = -3.4e38f;
    #pragma unroll 2
    for (int i = 0; i < RPW / 2; i += 2) {
        float4 p0 = sp4[i + 0];
        float4 p1 = sp4[i + 1];
        // g = px^2 + py^2 per ref point (amortized over 4 queries)
        float g0 = fmaf(p0.y, p0.y, p0.x * p0.x);
        float g1 = fmaf(p0.w, p0.w, p0.z * p0.z);
        float g2 = fmaf(p1.y, p1.y, p1.x * p1.x);
        float g3 = fmaf(p1.w, p1.w, p1.z * p1.z);
        float sa, sb, sc, sd;
        // query 0
        sa = fmaf(Qx0, p0.x, fmaf(Qy0, p0.y, -g0));
        sb = fmaf(Qx0, p0.z, fmaf(Qy0, p0.w, -g1));
        sc = fmaf(Qx0, p1.x, fmaf(Qy0, p1.y, -g2));
        sd = fmaf(Qx0, p1.z, fmaf(Qy0, p1.w, -g3));
        a0 = fmaxf(fmaxf(a0, sa), sb);               // -> v_max3
        a0 = fmaxf(fmaxf(a0, sc), sd);
        // query 1
        sa = fmaf(Qx1, p0.x, fmaf(Qy1, p0.y, -g0));
        sb = fmaf(Qx1, p0.z, fmaf(Qy1, p0.w, -g1));
        sc = fmaf(Qx1, p1.x, fmaf(Qy1, p1.y, -g2));
        sd = fmaf(Qx1, p1.z, fmaf(Qy1, p1.w, -g3));
        a1 = fmaxf(fmaxf(a1, sa), sb);
        a1 = fmaxf(fmaxf(a1, sc), sd);
        // query 2
        sa = fmaf(Qx2, p0.x, fmaf(Qy2, p0.y, -g0));
        sb = fmaf(Qx2, p0.z, fmaf(Qy2, p0.w, -g1));
        sc = fmaf(Qx2, p1.x, fmaf(Qy2, p1.y, -g2));
        sd = fmaf(Qx2, p1.z, fmaf(Qy2, p1.w, -g3));
        a2 = fmaxf(fmaxf(a2, sa), sb);
        a2 = fmaxf(fmaxf(a2, sc), sd);
        // query 3
        sa = fmaf(Qx3, p0.x, fmaf(Qy3, p0.y, -g0));
        sb = fmaf(Qx3, p0.z, fmaf(Qy3, p0.w, -g1));
        sc = fmaf(Qx3, p1.x, fmaf(Qy3, p1.y, -g2));
        sd = fmaf(Qx3, p1.z, fmaf(Qy3, p1.w, -g3));
        a3 = fmaxf(fmaxf(a3, sa), sb);
        a3 = fmaxf(fmaxf(a3, sc), sd);
    }
    smin[w][0 * 64 + lane] = a0;
    smin[w][1 * 64 + lane] = a1;
    smin[w][2 * 64 + lane] = a2;
    smin[w][3 * 64 + lane] = a3;
    __syncthreads();

    // Waves 0..3: wave j combines the 16 ref-slices for query row j,
    // converts max-s back to distance: d = sqrt(q^2 - s_max).
    if (w < QPL) {
        float v = smin[0][w * 64 + lane];
        #pragma unroll
        for (int ww = 1; ww < WAVES; ++ww)
            v = fmaxf(v, smin[ww][w * 64 + lane]);
        float q2 = (w == 0) ? q20 : (w == 1) ? q21 : (w == 2) ? q22 : q23;
        // NOTE: q2x of wave w's lanes correspond to query row w only for w's
        // own registers -- but each wave holds ALL FOUR query rows' q2 for its
        // lane, and row w uses index w: correct by construction.
        v = sqrtf(fmaxf(q2 - v, 0.f));
        #pragma unroll
        for (int off = 1; off < 64; off <<= 1)
            v += __shfl_xor(v, off);
        if (lane == 0) ssum[w] = v;
    }
    __syncthreads();
    if (tid == 0)
        partials[((size_t)dir * CH_B + b) * GRID_X + blockIdx.x] =
            ssum[0] + ssum[1] + ssum[2] + ssum[3];
}

__global__ __launch_bounds__(64) void chamfer_reduce_kernel(
    const float* __restrict__ partials, float* __restrict__ out, float scale)
{
    const int tid = threadIdx.x;
    const float4* p4 = (const float4*)partials;   // 256 floats = 64 float4
    float4 v = p4[tid];
    float s = v.x + v.y + v.z + v.w;
    #pragma unroll
    for (int off = 1; off < 64; off <<= 1)
        s += __shfl_xor(s, off);
    if (tid == 0) out[0] = s * scale;
}

extern "C" void kernel_launch(void* const* d_in, const int* in_sizes, int n_in,
                              void* d_out, int out_size, void* d_ws, size_t ws_size,
                              hipStream_t stream) {
    const float2* tp = (const float2*)d_in[0];  // target_points [B, M, 2]
    const float2* ap = (const float2*)d_in[1];  // actual_points [B, N, 2]
    float* out      = (float*)d_out;
    float* partials = (float*)d_ws;             // 256 floats, fully overwritten

    dim3 grid(GRID_X, CH_B, 2);                 // 256 blocks x 1024 threads
    chamfer_main_kernel<<<grid, THREADS, 0, stream>>>(tp, ap, partials);

    const float scale = 1.0f / (float)(CH_B * CH_N);   // M == N == 2048
    chamfer_reduce_kernel<<<1, 64, 0, stream>>>(partials, out, scale);
}